// Round 1
// baseline (733.828 us; speedup 1.0000x reference)
//
#include <hip/hip_runtime.h>
#include <math.h>

#define NN 50000
#define EE 800000
#define TT 2
#define HH 4
#define OUTF 128

constexpr float NEG_SLOPE = 0.2f;
constexpr float LN_EPS = 1e-12f;

// ---------------------------------------------------------------------------
// GEMM: fh[t] = feature @ W[t]   (fp32, register-tiled, K=128)
// block: 256 threads, tile 64 rows x 128 cols, K-chunks of 32
// thread (tcol=tid&15, trow=tid>>4): rows 4*trow..+3, cols 4*tcol..+3 and 64+4*tcol..+3
// ---------------------------------------------------------------------------
#define GM 64
#define KB 32
#define APAD 36
#define WPAD 132

__global__ __launch_bounds__(256) void gemm_fh(const float* __restrict__ A,
                                               const float* __restrict__ W,
                                               float* __restrict__ fh) {
  __shared__ float As[GM][APAD];
  __shared__ float Ws[KB][WPAD];
  const int t = blockIdx.y;
  const int row0 = blockIdx.x * GM;
  const int tid = threadIdx.x;
  const int tcol = tid & 15;
  const int trow = tid >> 4;
  const float* Wt = W + (size_t)t * 128 * 128;

  float acc[4][8];
#pragma unroll
  for (int i = 0; i < 4; ++i)
#pragma unroll
    for (int j = 0; j < 8; ++j) acc[i][j] = 0.f;

  for (int kk = 0; kk < 128; kk += KB) {
    // A chunk: 64 rows x 32 k
#pragma unroll
    for (int j = 0; j < 2; ++j) {
      int f = tid + 256 * j;
      int r = f >> 3, kq = f & 7;
      int grow = row0 + r;
      float4 v = make_float4(0.f, 0.f, 0.f, 0.f);
      if (grow < NN) v = *(const float4*)(A + (size_t)grow * 128 + kk + kq * 4);
      *(float4*)&As[r][kq * 4] = v;
    }
    // W chunk: 32 k x 128 cols
#pragma unroll
    for (int j = 0; j < 4; ++j) {
      int f = tid + 256 * j;
      int kq = f >> 5, c4 = f & 31;
      float4 v = *(const float4*)(Wt + (size_t)(kk + kq) * 128 + c4 * 4);
      *(float4*)&Ws[kq][c4 * 4] = v;
    }
    __syncthreads();
#pragma unroll
    for (int k = 0; k < KB; ++k) {
      float a0 = As[4 * trow + 0][k];
      float a1 = As[4 * trow + 1][k];
      float a2 = As[4 * trow + 2][k];
      float a3 = As[4 * trow + 3][k];
      float4 b0 = *(const float4*)&Ws[k][4 * tcol];
      float4 b1 = *(const float4*)&Ws[k][64 + 4 * tcol];
      acc[0][0] += a0 * b0.x; acc[0][1] += a0 * b0.y; acc[0][2] += a0 * b0.z; acc[0][3] += a0 * b0.w;
      acc[0][4] += a0 * b1.x; acc[0][5] += a0 * b1.y; acc[0][6] += a0 * b1.z; acc[0][7] += a0 * b1.w;
      acc[1][0] += a1 * b0.x; acc[1][1] += a1 * b0.y; acc[1][2] += a1 * b0.z; acc[1][3] += a1 * b0.w;
      acc[1][4] += a1 * b1.x; acc[1][5] += a1 * b1.y; acc[1][6] += a1 * b1.z; acc[1][7] += a1 * b1.w;
      acc[2][0] += a2 * b0.x; acc[2][1] += a2 * b0.y; acc[2][2] += a2 * b0.z; acc[2][3] += a2 * b0.w;
      acc[2][4] += a2 * b1.x; acc[2][5] += a2 * b1.y; acc[2][6] += a2 * b1.z; acc[2][7] += a2 * b1.w;
      acc[3][0] += a3 * b0.x; acc[3][1] += a3 * b0.y; acc[3][2] += a3 * b0.z; acc[3][3] += a3 * b0.w;
      acc[3][4] += a3 * b1.x; acc[3][5] += a3 * b1.y; acc[3][6] += a3 * b1.z; acc[3][7] += a3 * b1.w;
    }
    __syncthreads();
  }
#pragma unroll
  for (int i = 0; i < 4; ++i) {
    int grow = row0 + 4 * trow + i;
    if (grow < NN) {
      float* o = fh + ((size_t)t * NN + grow) * 128;
      *(float4*)(o + 4 * tcol) = make_float4(acc[i][0], acc[i][1], acc[i][2], acc[i][3]);
      *(float4*)(o + 64 + 4 * tcol) = make_float4(acc[i][4], acc[i][5], acc[i][6], acc[i][7]);
    }
  }
}

// ---------------------------------------------------------------------------
// el/er: per (t, n, h) dot of fh row-slice with attn vectors
// ---------------------------------------------------------------------------
__global__ __launch_bounds__(256) void compute_elr(const float* __restrict__ fh,
                                                   const float* __restrict__ al,
                                                   const float* __restrict__ ar,
                                                   float* __restrict__ el,
                                                   float* __restrict__ er) {
  int idx = blockIdx.x * 256 + threadIdx.x;
  if (idx >= TT * NN * HH) return;
  int t = idx / (NN * HH);
  int r = idx % (NN * HH);
  int n = r / HH, h = r % HH;
  const float4* f = (const float4*)(fh + ((size_t)t * NN + n) * 128 + h * 32);
  const float4* a4 = (const float4*)(al + (t * HH + h) * 32);
  const float4* b4 = (const float4*)(ar + (t * HH + h) * 32);
  float sl = 0.f, sr = 0.f;
#pragma unroll
  for (int i = 0; i < 8; ++i) {
    float4 fv = f[i], av = a4[i], bv = b4[i];
    sl += fv.x * av.x + fv.y * av.y + fv.z * av.z + fv.w * av.w;
    sr += fv.x * bv.x + fv.y * bv.y + fv.z * bv.z + fv.w * bv.w;
  }
  el[idx] = sl;
  er[idx] = sr;
}

// ---------------------------------------------------------------------------
// CSR build by dst: count -> scan -> scatter
// ---------------------------------------------------------------------------
__global__ __launch_bounds__(256) void count_edges(const int* __restrict__ dst,
                                                   int* __restrict__ counts) {
  int i = blockIdx.x * 256 + threadIdx.x;
  if (i < TT * EE) {
    int t = i / EE;
    atomicAdd(&counts[t * NN + dst[i]], 1);
  }
}

__global__ __launch_bounds__(1024) void scan_counts(const int* __restrict__ counts,
                                                    int* __restrict__ row_ptr) {
  __shared__ int smem[1024];
  __shared__ int carry;
  const int t = blockIdx.x;
  const int* c = counts + t * NN;
  int* rp = row_ptr + t * (NN + 1);
  const int tid = threadIdx.x;
  if (tid == 0) carry = 0;
  __syncthreads();
  for (int base = 0; base < NN; base += 1024) {
    int i = base + tid;
    int v = (i < NN) ? c[i] : 0;
    smem[tid] = v;
    __syncthreads();
    for (int off = 1; off < 1024; off <<= 1) {
      int add = (tid >= off) ? smem[tid - off] : 0;
      __syncthreads();
      smem[tid] += add;
      __syncthreads();
    }
    int incl = smem[tid];
    int c0 = carry;
    __syncthreads();
    if (i < NN) rp[i + 1] = c0 + incl;
    if (tid == 1023) carry = c0 + incl;
    __syncthreads();
  }
  if (tid == 0) rp[0] = 0;
}

__global__ __launch_bounds__(256) void scatter_edges(const int* __restrict__ src,
                                                     const int* __restrict__ dst,
                                                     const int* __restrict__ row_ptr,
                                                     int* __restrict__ cursor,
                                                     int* __restrict__ col_idx) {
  int i = blockIdx.x * 256 + threadIdx.x;
  if (i < TT * EE) {
    int t = i / EE;
    int d = dst[i];
    int pos = atomicAdd(&cursor[t * NN + d], 1);
    col_idx[(size_t)t * EE + row_ptr[t * (NN + 1) + d] + pos] = src[i];
  }
}

// ---------------------------------------------------------------------------
// Fused per-(node,type) kernel: one wave per item.
// lane -> channels d0=lane, d1=lane+64; heads h0=lane>>5, h1=h0+2.
// Pass 1: segment max. Pass 2: exp-sum + weighted fh aggregation.
// Then bias + LayerNorm(128) + ELU, write out[n][t][:].
// ---------------------------------------------------------------------------
__global__ __launch_bounds__(256) void gat_node(const float* __restrict__ fh,
                                                const float* __restrict__ el,
                                                const float* __restrict__ er,
                                                const int* __restrict__ row_ptr,
                                                const int* __restrict__ col_idx,
                                                const float* __restrict__ bias,
                                                const float* __restrict__ lnw,
                                                const float* __restrict__ lnb,
                                                float* __restrict__ out) {
  int item = blockIdx.x * 4 + (threadIdx.x >> 6);
  if (item >= TT * NN) return;
  const int t = item / NN;
  const int n = item % NN;
  const int lane = threadIdx.x & 63;
  const int d0 = lane, d1 = lane + 64;
  const int h0 = lane >> 5, h1 = h0 + 2;

  const int* rp = row_ptr + t * (NN + 1);
  const int eBeg = rp[n], eEnd = rp[n + 1];
  const int* col = col_idx + (size_t)t * EE;
  const float* elp = el + (size_t)t * NN * HH;
  const float* fhp = fh + (size_t)t * NN * 128;
  const float er0 = er[(size_t)t * NN * HH + (size_t)n * HH + h0];
  const float er1 = er[(size_t)t * NN * HH + (size_t)n * HH + h1];

  // pass 1: per-head max
  float m0 = -INFINITY, m1 = -INFINITY;
  for (int e = eBeg; e < eEnd; ++e) {
    int s = col[e];
    float x0 = elp[s * HH + h0] + er0;
    float x1 = elp[s * HH + h1] + er1;
    x0 = (x0 > 0.f) ? x0 : NEG_SLOPE * x0;
    x1 = (x1 > 0.f) ? x1 : NEG_SLOPE * x1;
    m0 = fmaxf(m0, x0);
    m1 = fmaxf(m1, x1);
  }

  // pass 2: exp-sum and weighted aggregation
  float den0 = 0.f, den1 = 0.f, acc0 = 0.f, acc1 = 0.f;
  for (int e = eBeg; e < eEnd; ++e) {
    int s = col[e];
    float x0 = elp[s * HH + h0] + er0;
    float x1 = elp[s * HH + h1] + er1;
    x0 = (x0 > 0.f) ? x0 : NEG_SLOPE * x0;
    x1 = (x1 > 0.f) ? x1 : NEG_SLOPE * x1;
    float a0 = __expf(x0 - m0);
    float a1 = __expf(x1 - m1);
    den0 += a0;
    den1 += a1;
    acc0 += fhp[(size_t)s * 128 + d0] * a0;
    acc1 += fhp[(size_t)s * 128 + d1] * a1;
  }

  float hv0 = ((den0 > 0.f) ? acc0 / den0 : 0.f) + bias[t * OUTF + d0];
  float hv1 = ((den1 > 0.f) ? acc1 / den1 : 0.f) + bias[t * OUTF + d1];

  // LayerNorm over 128 channels (2 per lane, 64 lanes)
  float s1 = hv0 + hv1;
#pragma unroll
  for (int off = 32; off >= 1; off >>= 1) s1 += __shfl_xor(s1, off, 64);
  float u = s1 * (1.f / OUTF);
  float dv0 = hv0 - u, dv1 = hv1 - u;
  float s2 = dv0 * dv0 + dv1 * dv1;
#pragma unroll
  for (int off = 32; off >= 1; off >>= 1) s2 += __shfl_xor(s2, off, 64);
  float rstd = rsqrtf(s2 * (1.f / OUTF) + LN_EPS);

  float y0 = lnw[t * OUTF + d0] * (dv0 * rstd) + lnb[t * OUTF + d0];
  float y1 = lnw[t * OUTF + d1] * (dv1 * rstd) + lnb[t * OUTF + d1];
  y0 = (y0 > 0.f) ? y0 : expm1f(y0);
  y1 = (y1 > 0.f) ? y1 : expm1f(y1);

  float* o = out + ((size_t)n * TT + t) * OUTF;
  o[d0] = y0;
  o[d1] = y1;
}

// ---------------------------------------------------------------------------
extern "C" void kernel_launch(void* const* d_in, const int* in_sizes, int n_in,
                              void* d_out, int out_size, void* d_ws, size_t ws_size,
                              hipStream_t stream) {
  const float* feature = (const float*)d_in[0];
  const int* src = (const int*)d_in[1];
  const int* dst = (const int*)d_in[2];
  const float* W = (const float*)d_in[3];
  const float* al = (const float*)d_in[4];
  const float* ar = (const float*)d_in[5];
  const float* bias = (const float*)d_in[6];
  const float* lnw = (const float*)d_in[7];
  const float* lnb = (const float*)d_in[8];
  float* out = (float*)d_out;

  char* ws = (char*)d_ws;
  size_t off = 0;
  auto carve = [&](size_t bytes) -> void* {
    void* p = ws + off;
    off += (bytes + 511) & ~(size_t)511;
    return p;
  };
  float* fh = (float*)carve((size_t)TT * NN * 128 * 4);       // 51.2 MB
  float* el = (float*)carve((size_t)TT * NN * HH * 4);        // 1.6 MB
  float* er = (float*)carve((size_t)TT * NN * HH * 4);        // 1.6 MB
  int* counts = (int*)carve((size_t)TT * NN * 4);             // 0.4 MB
  int* cursor = (int*)carve((size_t)TT * NN * 4);             // 0.4 MB
  int* row_ptr = (int*)carve((size_t)TT * (NN + 1) * 4);      // 0.4 MB
  int* col_idx = (int*)carve((size_t)TT * EE * 4);            // 6.4 MB

  hipMemsetAsync(counts, 0, (size_t)TT * NN * 4, stream);
  hipMemsetAsync(cursor, 0, (size_t)TT * NN * 4, stream);

  gemm_fh<<<dim3((NN + GM - 1) / GM, TT), 256, 0, stream>>>(feature, W, fh);
  compute_elr<<<(TT * NN * HH + 255) / 256, 256, 0, stream>>>(fh, al, ar, el, er);
  count_edges<<<(TT * EE + 255) / 256, 256, 0, stream>>>(dst, counts);
  scan_counts<<<TT, 1024, 0, stream>>>(counts, row_ptr);
  scatter_edges<<<(TT * EE + 255) / 256, 256, 0, stream>>>(src, dst, row_ptr, cursor, col_idx);
  gat_node<<<(TT * NN + 3) / 4, 256, 0, stream>>>(fh, el, er, row_ptr, col_idx,
                                                  bias, lnw, lnb, out);
}

// Round 3
// 445.344 us; speedup vs baseline: 1.6478x; 1.6478x over previous
//
#include <hip/hip_runtime.h>
#include <math.h>

#define NN 50000
#define EE 800000
#define TT 2
#define HH 4
#define OUTF 128
#define GRIDB 49   // ceil(NN/1024)

constexpr float NEG_SLOPE = 0.2f;
constexpr float LN_EPS = 1e-12f;

// ---------------------------------------------------------------------------
// GEMM: fh[t] = feature @ W[t]  (fp32, register-tiled) + fused el/er epilogue
// block: 256 threads, tile 64 rows x 128 cols, K-chunks of 32
// thread (tcol=tid&15, trow=tid>>4): rows 4*trow..+3, cols 4*tcol..+3 and 64+4*tcol..+3
// ---------------------------------------------------------------------------
#define GM 64
#define KB 32
#define APAD 36
#define WPAD 132

__global__ __launch_bounds__(256) void gemm_fh_elr(const float* __restrict__ A,
                                                   const float* __restrict__ W,
                                                   const float* __restrict__ al,
                                                   const float* __restrict__ ar,
                                                   float* __restrict__ fh,
                                                   float* __restrict__ el,
                                                   float* __restrict__ er) {
  __shared__ float As[GM][APAD];
  __shared__ float Ws[KB][WPAD];
  const int t = blockIdx.y;
  const int row0 = blockIdx.x * GM;
  const int tid = threadIdx.x;
  const int tcol = tid & 15;
  const int trow = tid >> 4;
  const float* Wt = W + (size_t)t * 128 * 128;

  float acc[4][8];
#pragma unroll
  for (int i = 0; i < 4; ++i)
#pragma unroll
    for (int j = 0; j < 8; ++j) acc[i][j] = 0.f;

  for (int kk = 0; kk < 128; kk += KB) {
#pragma unroll
    for (int j = 0; j < 2; ++j) {
      int f = tid + 256 * j;
      int r = f >> 3, kq = f & 7;
      int grow = row0 + r;
      float4 v = make_float4(0.f, 0.f, 0.f, 0.f);
      if (grow < NN) v = *(const float4*)(A + (size_t)grow * 128 + kk + kq * 4);
      *(float4*)&As[r][kq * 4] = v;
    }
#pragma unroll
    for (int j = 0; j < 4; ++j) {
      int f = tid + 256 * j;
      int kq = f >> 5, c4 = f & 31;
      float4 v = *(const float4*)(Wt + (size_t)(kk + kq) * 128 + c4 * 4);
      *(float4*)&Ws[kq][c4 * 4] = v;
    }
    __syncthreads();
#pragma unroll
    for (int k = 0; k < KB; ++k) {
      float a0 = As[4 * trow + 0][k];
      float a1 = As[4 * trow + 1][k];
      float a2 = As[4 * trow + 2][k];
      float a3 = As[4 * trow + 3][k];
      float4 b0 = *(const float4*)&Ws[k][4 * tcol];
      float4 b1 = *(const float4*)&Ws[k][64 + 4 * tcol];
      acc[0][0] += a0 * b0.x; acc[0][1] += a0 * b0.y; acc[0][2] += a0 * b0.z; acc[0][3] += a0 * b0.w;
      acc[0][4] += a0 * b1.x; acc[0][5] += a0 * b1.y; acc[0][6] += a0 * b1.z; acc[0][7] += a0 * b1.w;
      acc[1][0] += a1 * b0.x; acc[1][1] += a1 * b0.y; acc[1][2] += a1 * b0.z; acc[1][3] += a1 * b0.w;
      acc[1][4] += a1 * b1.x; acc[1][5] += a1 * b1.y; acc[1][6] += a1 * b1.z; acc[1][7] += a1 * b1.w;
      acc[2][0] += a2 * b0.x; acc[2][1] += a2 * b0.y; acc[2][2] += a2 * b0.z; acc[2][3] += a2 * b0.w;
      acc[2][4] += a2 * b1.x; acc[2][5] += a2 * b1.y; acc[2][6] += a2 * b1.z; acc[2][7] += a2 * b1.w;
      acc[3][0] += a3 * b0.x; acc[3][1] += a3 * b0.y; acc[3][2] += a3 * b0.z; acc[3][3] += a3 * b0.w;
      acc[3][4] += a3 * b1.x; acc[3][5] += a3 * b1.y; acc[3][6] += a3 * b1.z; acc[3][7] += a3 * b1.w;
    }
    __syncthreads();
  }
  // store fh tile
#pragma unroll
  for (int i = 0; i < 4; ++i) {
    int grow = row0 + 4 * trow + i;
    if (grow < NN) {
      float* o = fh + ((size_t)t * NN + grow) * 128;
      *(float4*)(o + 4 * tcol) = make_float4(acc[i][0], acc[i][1], acc[i][2], acc[i][3]);
      *(float4*)(o + 64 + 4 * tcol) = make_float4(acc[i][4], acc[i][5], acc[i][6], acc[i][7]);
    }
  }
  // fused el/er epilogue. Thread's low cols live in head ha=tcol>>3 (idx (4*tcol)&31),
  // high cols in head hb=2+ha. Reduce partials across the 8-thread tc-octet via shfl_xor.
  const int ha = tcol >> 3;
  const int ci = (4 * tcol) & 31;
  float4 alA = *(const float4*)(al + (size_t)(t * HH + ha) * 32 + ci);
  float4 arA = *(const float4*)(ar + (size_t)(t * HH + ha) * 32 + ci);
  float4 alB = *(const float4*)(al + (size_t)(t * HH + 2 + ha) * 32 + ci);
  float4 arB = *(const float4*)(ar + (size_t)(t * HH + 2 + ha) * 32 + ci);
#pragma unroll
  for (int i = 0; i < 4; ++i) {
    float pla = acc[i][0] * alA.x + acc[i][1] * alA.y + acc[i][2] * alA.z + acc[i][3] * alA.w;
    float pra = acc[i][0] * arA.x + acc[i][1] * arA.y + acc[i][2] * arA.z + acc[i][3] * arA.w;
    float plb = acc[i][4] * alB.x + acc[i][5] * alB.y + acc[i][6] * alB.z + acc[i][7] * alB.w;
    float prb = acc[i][4] * arB.x + acc[i][5] * arB.y + acc[i][6] * arB.z + acc[i][7] * arB.w;
#pragma unroll
    for (int off = 1; off <= 4; off <<= 1) {
      pla += __shfl_xor(pla, off, 64);
      pra += __shfl_xor(pra, off, 64);
      plb += __shfl_xor(plb, off, 64);
      prb += __shfl_xor(prb, off, 64);
    }
    if ((tcol & 7) == 0) {
      int row = row0 + 4 * trow + i;
      if (row < NN) {
        size_t base = ((size_t)t * NN + row) * HH;
        el[base + ha] = pla;
        er[base + ha] = pra;
        el[base + 2 + ha] = plb;
        er[base + 2 + ha] = prb;
      }
    }
  }
}

// ---------------------------------------------------------------------------
// CSR build: count -> 3-phase scan -> scatter (cursor pre-filled w/ row starts)
// ---------------------------------------------------------------------------
__global__ __launch_bounds__(256) void count_edges(const int* __restrict__ dst,
                                                   int* __restrict__ counts) {
  const int t = blockIdx.y;
  int i4 = (blockIdx.x * 256 + threadIdx.x) * 4;
  if (i4 + 3 < EE) {
    int4 d = *(const int4*)(dst + (size_t)t * EE + i4);
    atomicAdd(&counts[t * NN + d.x], 1);
    atomicAdd(&counts[t * NN + d.y], 1);
    atomicAdd(&counts[t * NN + d.z], 1);
    atomicAdd(&counts[t * NN + d.w], 1);
  } else {
    for (int j = 0; j < 4 && i4 + j < EE; ++j)
      atomicAdd(&counts[t * NN + dst[(size_t)t * EE + i4 + j]], 1);
  }
}

// phase A: per-1024-chunk inclusive scan (256 thr x 4 elems) + chunk totals
__global__ __launch_bounds__(256) void scan_a(const int* __restrict__ counts,
                                              int* __restrict__ rp,
                                              int* __restrict__ bsum) {
  const int t = blockIdx.y, b = blockIdx.x, tid = threadIdx.x;
  const int i0 = b * 1024 + tid * 4;
  const int* c = counts + t * NN;
  int c0 = 0, c1 = 0, c2 = 0, c3 = 0;
  if (i0 + 3 < NN) {
    int4 v = *(const int4*)(c + i0);
    c0 = v.x; c1 = v.y; c2 = v.z; c3 = v.w;
  } else {
    if (i0 + 0 < NN) c0 = c[i0 + 0];
    if (i0 + 1 < NN) c1 = c[i0 + 1];
    if (i0 + 2 < NN) c2 = c[i0 + 2];
    if (i0 + 3 < NN) c3 = c[i0 + 3];
  }
  int p0 = c0, p1 = p0 + c1, p2 = p1 + c2, p3 = p2 + c3;
  int s = p3;
  const int lane = tid & 63;
#pragma unroll
  for (int off = 1; off <= 32; off <<= 1) {
    int v = __shfl_up(s, off, 64);
    if (lane >= off) s += v;
  }
  __shared__ int wsum[4];
  const int w = tid >> 6;
  if (lane == 63) wsum[w] = s;
  __syncthreads();
  int woff = 0;
  for (int k = 0; k < w; ++k) woff += wsum[k];
  int excl = woff + s - p3;
  int* rpt = rp + t * (NN + 1);
  if (i0 + 0 < NN) rpt[i0 + 1] = excl + p0;
  if (i0 + 1 < NN) rpt[i0 + 2] = excl + p1;
  if (i0 + 2 < NN) rpt[i0 + 3] = excl + p2;
  if (i0 + 3 < NN) rpt[i0 + 4] = excl + p3;
  if (tid == 255) bsum[t * GRIDB + b] = woff + s;
}

// phase B: exclusive-scan the GRIDB chunk totals per type (one small block)
__global__ __launch_bounds__(64) void scan_b(const int* __restrict__ bsum,
                                             int* __restrict__ boff) {
  const int lane = threadIdx.x;
  for (int t = 0; t < TT; ++t) {
    int orig = (lane < GRIDB) ? bsum[t * GRIDB + lane] : 0;
    int s = orig;
#pragma unroll
    for (int off = 1; off <= 32; off <<= 1) {
      int v = __shfl_up(s, off, 64);
      if (lane >= off) s += v;
    }
    if (lane < GRIDB) boff[t * GRIDB + lane] = s - orig;
  }
}

// phase C: add chunk offsets; also pre-fill cursor with row starts
__global__ __launch_bounds__(256) void scan_c(int* __restrict__ rp,
                                              const int* __restrict__ boff,
                                              int* __restrict__ cursor) {
  int idx = blockIdx.x * 256 + threadIdx.x;
  if (idx >= TT * NN) return;
  int t = idx / NN, i = idx % NN;
  int v = rp[t * (NN + 1) + i + 1] + boff[t * GRIDB + (i >> 10)];
  rp[t * (NN + 1) + i + 1] = v;
  if (i + 1 < NN) cursor[t * NN + i + 1] = v;
  if (i == 0) {
    rp[t * (NN + 1)] = 0;
    cursor[t * NN] = 0;
  }
}

__global__ __launch_bounds__(256) void scatter_edges(const int* __restrict__ src,
                                                     const int* __restrict__ dst,
                                                     int* __restrict__ cursor,
                                                     int* __restrict__ col_idx) {
  const int t = blockIdx.y;
  int i4 = (blockIdx.x * 256 + threadIdx.x) * 4;
  int* col = col_idx + (size_t)t * EE;
  if (i4 + 3 < EE) {
    int4 d = *(const int4*)(dst + (size_t)t * EE + i4);
    int4 sv = *(const int4*)(src + (size_t)t * EE + i4);
    col[atomicAdd(&cursor[t * NN + d.x], 1)] = sv.x;
    col[atomicAdd(&cursor[t * NN + d.y], 1)] = sv.y;
    col[atomicAdd(&cursor[t * NN + d.z], 1)] = sv.z;
    col[atomicAdd(&cursor[t * NN + d.w], 1)] = sv.w;
  } else {
    for (int j = 0; j < 4 && i4 + j < EE; ++j) {
      int d = dst[(size_t)t * EE + i4 + j];
      col[atomicAdd(&cursor[t * NN + d], 1)] = src[(size_t)t * EE + i4 + j];
    }
  }
}

// ---------------------------------------------------------------------------
// Fused per-(node,type) kernel: 32 lanes per item, 2 items per wave.
// Single pass (no segment-max: |e| <= ~5 so exp is safe; softmax shift-inv).
// lane l (0..31): channels 4l..4l+3 (one float4), head h = l>>3.
// Then bias + LayerNorm(128, across 32 lanes) + ELU.
// ---------------------------------------------------------------------------
__global__ __launch_bounds__(256) void gat_node(const float* __restrict__ fh,
                                                const float* __restrict__ el,
                                                const float* __restrict__ er,
                                                const int* __restrict__ rp,
                                                const int* __restrict__ col_idx,
                                                const float* __restrict__ bias,
                                                const float* __restrict__ lnw,
                                                const float* __restrict__ lnb,
                                                float* __restrict__ out) {
  const int item = blockIdx.x * 8 + (threadIdx.x >> 5);  // grid covers TT*NN exactly
  const int t = item / NN;
  const int n = item % NN;
  const int l = threadIdx.x & 31;
  const int c0 = 4 * l;
  const int h = l >> 3;

  const int* rpt = rp + t * (NN + 1);
  const int eBeg = rpt[n], eEnd = rpt[n + 1];
  const int* col = col_idx + (size_t)t * EE;
  const float* elp = el + (size_t)t * NN * HH;
  const float* fhp = fh + (size_t)t * NN * 128;
  const float erh = er[((size_t)t * NN + n) * HH + h];

  float den = 0.f;
  float ax = 0.f, ay = 0.f, az = 0.f, aw = 0.f;
#pragma unroll 4
  for (int e = eBeg; e < eEnd; ++e) {
    int s = col[e];
    float x = elp[(size_t)s * HH + h] + erh;
    x = (x > 0.f) ? x : NEG_SLOPE * x;
    float a = __expf(x);
    den += a;
    float4 f = *(const float4*)(fhp + (size_t)s * 128 + c0);
    ax += a * f.x; ay += a * f.y; az += a * f.z; aw += a * f.w;
  }
  float inv = (den > 0.f) ? 1.f / den : 0.f;
  float hx = ax * inv + bias[t * OUTF + c0 + 0];
  float hy = ay * inv + bias[t * OUTF + c0 + 1];
  float hz = az * inv + bias[t * OUTF + c0 + 2];
  float hw = aw * inv + bias[t * OUTF + c0 + 3];

  // LayerNorm over 128 channels (4 per lane, 32 lanes)
  float s1 = hx + hy + hz + hw;
#pragma unroll
  for (int off = 16; off >= 1; off >>= 1) s1 += __shfl_xor(s1, off, 32);
  float u = s1 * (1.f / OUTF);
  float dx = hx - u, dy = hy - u, dz = hz - u, dw = hw - u;
  float s2 = dx * dx + dy * dy + dz * dz + dw * dw;
#pragma unroll
  for (int off = 16; off >= 1; off >>= 1) s2 += __shfl_xor(s2, off, 32);
  float rstd = rsqrtf(s2 * (1.f / OUTF) + LN_EPS);

  float4 wv = *(const float4*)(lnw + t * OUTF + c0);
  float4 bv = *(const float4*)(lnb + t * OUTF + c0);
  float y0 = wv.x * (dx * rstd) + bv.x;
  float y1 = wv.y * (dy * rstd) + bv.y;
  float y2 = wv.z * (dz * rstd) + bv.z;
  float y3 = wv.w * (dw * rstd) + bv.w;
  y0 = (y0 > 0.f) ? y0 : expm1f(y0);
  y1 = (y1 > 0.f) ? y1 : expm1f(y1);
  y2 = (y2 > 0.f) ? y2 : expm1f(y2);
  y3 = (y3 > 0.f) ? y3 : expm1f(y3);

  *(float4*)(out + ((size_t)n * TT + t) * OUTF + c0) = make_float4(y0, y1, y2, y3);
}

// ---------------------------------------------------------------------------
extern "C" void kernel_launch(void* const* d_in, const int* in_sizes, int n_in,
                              void* d_out, int out_size, void* d_ws, size_t ws_size,
                              hipStream_t stream) {
  const float* feature = (const float*)d_in[0];
  const int* src = (const int*)d_in[1];
  const int* dst = (const int*)d_in[2];
  const float* W = (const float*)d_in[3];
  const float* al = (const float*)d_in[4];
  const float* ar = (const float*)d_in[5];
  const float* bias = (const float*)d_in[6];
  const float* lnw = (const float*)d_in[7];
  const float* lnb = (const float*)d_in[8];
  float* out = (float*)d_out;

  char* ws = (char*)d_ws;
  size_t off = 0;
  auto carve = [&](size_t bytes) -> void* {
    void* p = ws + off;
    off += (bytes + 511) & ~(size_t)511;
    return p;
  };
  float* fh = (float*)carve((size_t)TT * NN * 128 * 4);   // 51.2 MB
  float* el = (float*)carve((size_t)TT * NN * HH * 4);
  float* er = (float*)carve((size_t)TT * NN * HH * 4);
  int* counts = (int*)carve((size_t)TT * NN * 4);
  int* cursor = (int*)carve((size_t)TT * NN * 4);
  int* row_ptr = (int*)carve((size_t)TT * (NN + 1) * 4);
  int* col_idx = (int*)carve((size_t)TT * EE * 4);        // 6.4 MB
  int* bsum = (int*)carve((size_t)TT * GRIDB * 4);
  int* boff = (int*)carve((size_t)TT * GRIDB * 4);

  hipMemsetAsync(counts, 0, (size_t)TT * NN * 4, stream);

  gemm_fh_elr<<<dim3((NN + GM - 1) / GM, TT), 256, 0, stream>>>(feature, W, al, ar, fh, el, er);
  count_edges<<<dim3((EE / 4 + 255) / 256, TT), 256, 0, stream>>>(dst, counts);
  scan_a<<<dim3(GRIDB, TT), 256, 0, stream>>>(counts, row_ptr, bsum);
  scan_b<<<1, 64, 0, stream>>>(bsum, boff);
  scan_c<<<(TT * NN + 255) / 256, 256, 0, stream>>>(row_ptr, boff, cursor);
  scatter_edges<<<dim3((EE / 4 + 255) / 256, TT), 256, 0, stream>>>(src, dst, cursor, col_idx);
  gat_node<<<(TT * NN) / 8, 256, 0, stream>>>(fh, el, er, row_ptr, col_idx,
                                              bias, lnw, lnb, out);
}

// Round 4
// 364.370 us; speedup vs baseline: 2.0140x; 1.2222x over previous
//
#include <hip/hip_runtime.h>
#include <math.h>

#define NN 50000
#define EE 800000
#define TT 2
#define HH 4
#define OUTF 128

constexpr float NEG_SLOPE = 0.2f;
constexpr float LN_EPS = 1e-12f;

// ---------------------------------------------------------------------------
// GEMM: fh[t] = feature @ W[t]  (fp32, register-tiled) + fused el/er epilogue
// block: 256 threads, tile 64 rows x 128 cols, K-chunks of 32
// ---------------------------------------------------------------------------
#define GM 64
#define KB 32
#define APAD 36
#define WPAD 132

__global__ __launch_bounds__(256) void gemm_fh_elr(const float* __restrict__ A,
                                                   const float* __restrict__ W,
                                                   const float* __restrict__ al,
                                                   const float* __restrict__ ar,
                                                   float* __restrict__ fh,
                                                   float* __restrict__ el,
                                                   float* __restrict__ er) {
  __shared__ float As[GM][APAD];
  __shared__ float Ws[KB][WPAD];
  const int t = blockIdx.y;
  const int row0 = blockIdx.x * GM;
  const int tid = threadIdx.x;
  const int tcol = tid & 15;
  const int trow = tid >> 4;
  const float* Wt = W + (size_t)t * 128 * 128;

  float acc[4][8];
#pragma unroll
  for (int i = 0; i < 4; ++i)
#pragma unroll
    for (int j = 0; j < 8; ++j) acc[i][j] = 0.f;

  for (int kk = 0; kk < 128; kk += KB) {
#pragma unroll
    for (int j = 0; j < 2; ++j) {
      int f = tid + 256 * j;
      int r = f >> 3, kq = f & 7;
      int grow = row0 + r;
      float4 v = make_float4(0.f, 0.f, 0.f, 0.f);
      if (grow < NN) v = *(const float4*)(A + (size_t)grow * 128 + kk + kq * 4);
      *(float4*)&As[r][kq * 4] = v;
    }
#pragma unroll
    for (int j = 0; j < 4; ++j) {
      int f = tid + 256 * j;
      int kq = f >> 5, c4 = f & 31;
      float4 v = *(const float4*)(Wt + (size_t)(kk + kq) * 128 + c4 * 4);
      *(float4*)&Ws[kq][c4 * 4] = v;
    }
    __syncthreads();
#pragma unroll
    for (int k = 0; k < KB; ++k) {
      float a0 = As[4 * trow + 0][k];
      float a1 = As[4 * trow + 1][k];
      float a2 = As[4 * trow + 2][k];
      float a3 = As[4 * trow + 3][k];
      float4 b0 = *(const float4*)&Ws[k][4 * tcol];
      float4 b1 = *(const float4*)&Ws[k][64 + 4 * tcol];
      acc[0][0] += a0 * b0.x; acc[0][1] += a0 * b0.y; acc[0][2] += a0 * b0.z; acc[0][3] += a0 * b0.w;
      acc[0][4] += a0 * b1.x; acc[0][5] += a0 * b1.y; acc[0][6] += a0 * b1.z; acc[0][7] += a0 * b1.w;
      acc[1][0] += a1 * b0.x; acc[1][1] += a1 * b0.y; acc[1][2] += a1 * b0.z; acc[1][3] += a1 * b0.w;
      acc[1][4] += a1 * b1.x; acc[1][5] += a1 * b1.y; acc[1][6] += a1 * b1.z; acc[1][7] += a1 * b1.w;
      acc[2][0] += a2 * b0.x; acc[2][1] += a2 * b0.y; acc[2][2] += a2 * b0.z; acc[2][3] += a2 * b0.w;
      acc[2][4] += a2 * b1.x; acc[2][5] += a2 * b1.y; acc[2][6] += a2 * b1.z; acc[2][7] += a2 * b1.w;
      acc[3][0] += a3 * b0.x; acc[3][1] += a3 * b0.y; acc[3][2] += a3 * b0.z; acc[3][3] += a3 * b0.w;
      acc[3][4] += a3 * b1.x; acc[3][5] += a3 * b1.y; acc[3][6] += a3 * b1.z; acc[3][7] += a3 * b1.w;
    }
    __syncthreads();
  }
#pragma unroll
  for (int i = 0; i < 4; ++i) {
    int grow = row0 + 4 * trow + i;
    if (grow < NN) {
      float* o = fh + ((size_t)t * NN + grow) * 128;
      *(float4*)(o + 4 * tcol) = make_float4(acc[i][0], acc[i][1], acc[i][2], acc[i][3]);
      *(float4*)(o + 64 + 4 * tcol) = make_float4(acc[i][4], acc[i][5], acc[i][6], acc[i][7]);
    }
  }
  // fused el/er epilogue (reduce across the 8-thread tcol-octet)
  const int ha = tcol >> 3;
  const int ci = (4 * tcol) & 31;
  float4 alA = *(const float4*)(al + (size_t)(t * HH + ha) * 32 + ci);
  float4 arA = *(const float4*)(ar + (size_t)(t * HH + ha) * 32 + ci);
  float4 alB = *(const float4*)(al + (size_t)(t * HH + 2 + ha) * 32 + ci);
  float4 arB = *(const float4*)(ar + (size_t)(t * HH + 2 + ha) * 32 + ci);
#pragma unroll
  for (int i = 0; i < 4; ++i) {
    float pla = acc[i][0] * alA.x + acc[i][1] * alA.y + acc[i][2] * alA.z + acc[i][3] * alA.w;
    float pra = acc[i][0] * arA.x + acc[i][1] * arA.y + acc[i][2] * arA.z + acc[i][3] * arA.w;
    float plb = acc[i][4] * alB.x + acc[i][5] * alB.y + acc[i][6] * alB.z + acc[i][7] * alB.w;
    float prb = acc[i][4] * arB.x + acc[i][5] * arB.y + acc[i][6] * arB.z + acc[i][7] * arB.w;
#pragma unroll
    for (int off = 1; off <= 4; off <<= 1) {
      pla += __shfl_xor(pla, off, 64);
      pra += __shfl_xor(pra, off, 64);
      plb += __shfl_xor(plb, off, 64);
      prb += __shfl_xor(prb, off, 64);
    }
    if ((tcol & 7) == 0) {
      int row = row0 + 4 * trow + i;
      if (row < NN) {
        size_t base = ((size_t)t * NN + row) * HH;
        el[base + ha] = pla;
        er[base + ha] = pra;
        el[base + 2 + ha] = plb;
        er[base + 2 + ha] = prb;
      }
    }
  }
}

// ---------------------------------------------------------------------------
// Per-dst linked list: rec[i] = {next_edge, src[i]}, head[t*NN+d] = last edge.
// Sequential 32B/thread rec writes; only the 0.4MB head array sees atomics.
// ---------------------------------------------------------------------------
__global__ __launch_bounds__(256) void build_list(const int* __restrict__ src,
                                                  const int* __restrict__ dst,
                                                  int* __restrict__ head,
                                                  int2* __restrict__ rec) {
  const int t = blockIdx.y;
  int i4 = (blockIdx.x * 256 + threadIdx.x) * 4;
  if (i4 >= EE) return;
  int2* recT = rec + (size_t)t * EE;
  int* headT = head + t * NN;
  if (i4 + 3 < EE) {
    int4 d = *(const int4*)(dst + (size_t)t * EE + i4);
    int4 s = *(const int4*)(src + (size_t)t * EE + i4);
    int o0 = atomicExch(&headT[d.x], i4 + 0);
    int o1 = atomicExch(&headT[d.y], i4 + 1);
    int o2 = atomicExch(&headT[d.z], i4 + 2);
    int o3 = atomicExch(&headT[d.w], i4 + 3);
    *(int4*)&recT[i4] = make_int4(o0, s.x, o1, s.y);
    *(int4*)&recT[i4 + 2] = make_int4(o2, s.z, o3, s.w);
  } else {
    for (int j = 0; j < 4 && i4 + j < EE; ++j) {
      int d = dst[(size_t)t * EE + i4 + j];
      int s = src[(size_t)t * EE + i4 + j];
      int o = atomicExch(&headT[d], i4 + j);
      recT[i4 + j] = make_int2(o, s);
    }
  }
}

// ---------------------------------------------------------------------------
// Fused per-(node,type) kernel: 32 lanes per item, 8 items per block.
// Walk the dst linked list; single-pass softmax (no max shift: |e| small).
// lane l: channels 4l..4l+3 (one float4), head h = l>>3.
// Then bias + LayerNorm(128) + ELU.
// ---------------------------------------------------------------------------
__global__ __launch_bounds__(256) void gat_node(const float* __restrict__ fh,
                                                const float* __restrict__ el,
                                                const float* __restrict__ er,
                                                const int* __restrict__ head,
                                                const int2* __restrict__ rec,
                                                const float* __restrict__ bias,
                                                const float* __restrict__ lnw,
                                                const float* __restrict__ lnb,
                                                float* __restrict__ out) {
  const int item = blockIdx.x * 8 + (threadIdx.x >> 5);  // grid covers TT*NN exactly
  const int t = item / NN;
  const int n = item % NN;
  const int l = threadIdx.x & 31;
  const int c0 = 4 * l;
  const int h = l >> 3;

  const int2* recT = rec + (size_t)t * EE;
  const float* elp = el + (size_t)t * NN * HH;
  const float* fhp = fh + (size_t)t * NN * 128;
  const float erh = er[((size_t)t * NN + n) * HH + h];

  float den = 0.f;
  float ax = 0.f, ay = 0.f, az = 0.f, aw = 0.f;
  int e = head[t * NN + n];
  while (e >= 0) {
    int2 r = recT[e];           // broadcast 8B load: {next, src}
    int s = r.y;
    float x = elp[(size_t)s * HH + h] + erh;
    x = (x > 0.f) ? x : NEG_SLOPE * x;
    float a = __expf(x);
    den += a;
    float4 f = *(const float4*)(fhp + (size_t)s * 128 + c0);
    ax += a * f.x; ay += a * f.y; az += a * f.z; aw += a * f.w;
    e = r.x;
  }
  float inv = (den > 0.f) ? 1.f / den : 0.f;
  float hx = ax * inv + bias[t * OUTF + c0 + 0];
  float hy = ay * inv + bias[t * OUTF + c0 + 1];
  float hz = az * inv + bias[t * OUTF + c0 + 2];
  float hw = aw * inv + bias[t * OUTF + c0 + 3];

  // LayerNorm over 128 channels (4 per lane, 32 lanes)
  float s1 = hx + hy + hz + hw;
#pragma unroll
  for (int off = 16; off >= 1; off >>= 1) s1 += __shfl_xor(s1, off, 32);
  float u = s1 * (1.f / OUTF);
  float dx = hx - u, dy = hy - u, dz = hz - u, dw = hw - u;
  float s2 = dx * dx + dy * dy + dz * dz + dw * dw;
#pragma unroll
  for (int off = 16; off >= 1; off >>= 1) s2 += __shfl_xor(s2, off, 32);
  float rstd = rsqrtf(s2 * (1.f / OUTF) + LN_EPS);

  float4 wv = *(const float4*)(lnw + t * OUTF + c0);
  float4 bv = *(const float4*)(lnb + t * OUTF + c0);
  float y0 = wv.x * (dx * rstd) + bv.x;
  float y1 = wv.y * (dy * rstd) + bv.y;
  float y2 = wv.z * (dz * rstd) + bv.z;
  float y3 = wv.w * (dw * rstd) + bv.w;
  y0 = (y0 > 0.f) ? y0 : expm1f(y0);
  y1 = (y1 > 0.f) ? y1 : expm1f(y1);
  y2 = (y2 > 0.f) ? y2 : expm1f(y2);
  y3 = (y3 > 0.f) ? y3 : expm1f(y3);

  *(float4*)(out + ((size_t)n * TT + t) * OUTF + c0) = make_float4(y0, y1, y2, y3);
}

// ---------------------------------------------------------------------------
extern "C" void kernel_launch(void* const* d_in, const int* in_sizes, int n_in,
                              void* d_out, int out_size, void* d_ws, size_t ws_size,
                              hipStream_t stream) {
  const float* feature = (const float*)d_in[0];
  const int* src = (const int*)d_in[1];
  const int* dst = (const int*)d_in[2];
  const float* W = (const float*)d_in[3];
  const float* al = (const float*)d_in[4];
  const float* ar = (const float*)d_in[5];
  const float* bias = (const float*)d_in[6];
  const float* lnw = (const float*)d_in[7];
  const float* lnb = (const float*)d_in[8];
  float* out = (float*)d_out;

  char* ws = (char*)d_ws;
  size_t off = 0;
  auto carve = [&](size_t bytes) -> void* {
    void* p = ws + off;
    off += (bytes + 511) & ~(size_t)511;
    return p;
  };
  float* fh = (float*)carve((size_t)TT * NN * 128 * 4);   // 51.2 MB
  float* el = (float*)carve((size_t)TT * NN * HH * 4);
  float* er = (float*)carve((size_t)TT * NN * HH * 4);
  int* head = (int*)carve((size_t)TT * NN * 4);           // 0.4 MB
  int2* rec = (int2*)carve((size_t)TT * EE * 8);          // 12.8 MB

  hipMemsetAsync(head, 0xFF, (size_t)TT * NN * 4, stream);  // head = -1

  gemm_fh_elr<<<dim3((NN + GM - 1) / GM, TT), 256, 0, stream>>>(feature, W, al, ar, fh, el, er);
  build_list<<<dim3((EE / 4 + 255) / 256, TT), 256, 0, stream>>>(src, dst, head, rec);
  gat_node<<<(TT * NN) / 8, 256, 0, stream>>>(fh, el, er, head, rec,
                                              bias, lnw, lnb, out);
}

// Round 8
// 358.827 us; speedup vs baseline: 2.0451x; 1.0154x over previous
//
#include <hip/hip_runtime.h>
#include <math.h>

#define NN 50000
#define EE 800000
#define TT 2
#define HH 4
#define OUTF 128

constexpr float NEG_SLOPE = 0.2f;
constexpr float LN_EPS = 1e-12f;

// ---------------------------------------------------------------------------
// GEMM: fh[t] = feature @ W[t]  (fp32, register-tiled) + fused el/er epilogue
// block: 256 threads, tile 64 rows x 128 cols, K-chunks of 32
// ---------------------------------------------------------------------------
#define GM 64
#define KB 32
#define APAD 36
#define WPAD 132

__global__ __launch_bounds__(256) void gemm_fh_elr(const float* __restrict__ A,
                                                   const float* __restrict__ W,
                                                   const float* __restrict__ al,
                                                   const float* __restrict__ ar,
                                                   float* __restrict__ fh,
                                                   float* __restrict__ el,
                                                   float* __restrict__ er) {
  __shared__ float As[GM][APAD];
  __shared__ float Ws[KB][WPAD];
  const int t = blockIdx.y;
  const int row0 = blockIdx.x * GM;
  const int tid = threadIdx.x;
  const int tcol = tid & 15;
  const int trow = tid >> 4;
  const float* Wt = W + (size_t)t * 128 * 128;

  float acc[4][8];
#pragma unroll
  for (int i = 0; i < 4; ++i)
#pragma unroll
    for (int j = 0; j < 8; ++j) acc[i][j] = 0.f;

  for (int kk = 0; kk < 128; kk += KB) {
#pragma unroll
    for (int j = 0; j < 2; ++j) {
      int f = tid + 256 * j;
      int r = f >> 3, kq = f & 7;
      int grow = row0 + r;
      float4 v = make_float4(0.f, 0.f, 0.f, 0.f);
      if (grow < NN) v = *(const float4*)(A + (size_t)grow * 128 + kk + kq * 4);
      *(float4*)&As[r][kq * 4] = v;
    }
#pragma unroll
    for (int j = 0; j < 4; ++j) {
      int f = tid + 256 * j;
      int kq = f >> 5, c4 = f & 31;
      float4 v = *(const float4*)(Wt + (size_t)(kk + kq) * 128 + c4 * 4);
      *(float4*)&Ws[kq][c4 * 4] = v;
    }
    __syncthreads();
#pragma unroll
    for (int k = 0; k < KB; ++k) {
      float a0 = As[4 * trow + 0][k];
      float a1 = As[4 * trow + 1][k];
      float a2 = As[4 * trow + 2][k];
      float a3 = As[4 * trow + 3][k];
      float4 b0 = *(const float4*)&Ws[k][4 * tcol];
      float4 b1 = *(const float4*)&Ws[k][64 + 4 * tcol];
      acc[0][0] += a0 * b0.x; acc[0][1] += a0 * b0.y; acc[0][2] += a0 * b0.z; acc[0][3] += a0 * b0.w;
      acc[0][4] += a0 * b1.x; acc[0][5] += a0 * b1.y; acc[0][6] += a0 * b1.z; acc[0][7] += a0 * b1.w;
      acc[1][0] += a1 * b0.x; acc[1][1] += a1 * b0.y; acc[1][2] += a1 * b0.z; acc[1][3] += a1 * b0.w;
      acc[1][4] += a1 * b1.x; acc[1][5] += a1 * b1.y; acc[1][6] += a1 * b1.z; acc[1][7] += a1 * b1.w;
      acc[2][0] += a2 * b0.x; acc[2][1] += a2 * b0.y; acc[2][2] += a2 * b0.z; acc[2][3] += a2 * b0.w;
      acc[2][4] += a2 * b1.x; acc[2][5] += a2 * b1.y; acc[2][6] += a2 * b1.z; acc[2][7] += a2 * b1.w;
      acc[3][0] += a3 * b0.x; acc[3][1] += a3 * b0.y; acc[3][2] += a3 * b0.z; acc[3][3] += a3 * b0.w;
      acc[3][4] += a3 * b1.x; acc[3][5] += a3 * b1.y; acc[3][6] += a3 * b1.z; acc[3][7] += a3 * b1.w;
    }
    __syncthreads();
  }
#pragma unroll
  for (int i = 0; i < 4; ++i) {
    int grow = row0 + 4 * trow + i;
    if (grow < NN) {
      float* o = fh + ((size_t)t * NN + grow) * 128;
      *(float4*)(o + 4 * tcol) = make_float4(acc[i][0], acc[i][1], acc[i][2], acc[i][3]);
      *(float4*)(o + 64 + 4 * tcol) = make_float4(acc[i][4], acc[i][5], acc[i][6], acc[i][7]);
    }
  }
  // fused el/er epilogue (reduce across the 8-thread tcol-octet)
  const int ha = tcol >> 3;
  const int ci = (4 * tcol) & 31;
  float4 alA = *(const float4*)(al + (size_t)(t * HH + ha) * 32 + ci);
  float4 arA = *(const float4*)(ar + (size_t)(t * HH + ha) * 32 + ci);
  float4 alB = *(const float4*)(al + (size_t)(t * HH + 2 + ha) * 32 + ci);
  float4 arB = *(const float4*)(ar + (size_t)(t * HH + 2 + ha) * 32 + ci);
#pragma unroll
  for (int i = 0; i < 4; ++i) {
    float pla = acc[i][0] * alA.x + acc[i][1] * alA.y + acc[i][2] * alA.z + acc[i][3] * alA.w;
    float pra = acc[i][0] * arA.x + acc[i][1] * arA.y + acc[i][2] * arA.z + acc[i][3] * arA.w;
    float plb = acc[i][4] * alB.x + acc[i][5] * alB.y + acc[i][6] * alB.z + acc[i][7] * alB.w;
    float prb = acc[i][4] * arB.x + acc[i][5] * arB.y + acc[i][6] * arB.z + acc[i][7] * arB.w;
#pragma unroll
    for (int off = 1; off <= 4; off <<= 1) {
      pla += __shfl_xor(pla, off, 64);
      pra += __shfl_xor(pra, off, 64);
      plb += __shfl_xor(plb, off, 64);
      prb += __shfl_xor(prb, off, 64);
    }
    if ((tcol & 7) == 0) {
      int row = row0 + 4 * trow + i;
      if (row < NN) {
        size_t base = ((size_t)t * NN + row) * HH;
        el[base + ha] = pla;
        er[base + ha] = pra;
        el[base + 2 + ha] = plb;
        er[base + 2 + ha] = prb;
      }
    }
  }
}

// ---------------------------------------------------------------------------
// TWO per-dst linked lists (edge parity i&1) with fat records (32B):
//   rec[e] = {next, src, el[src][0..3], pad2}
// One 64B line per chain hop carries everything but fh. head pairs (int2 per
// node, 0.8MB total) get atomics; rec writes are sequential full lines.
// ---------------------------------------------------------------------------
__global__ __launch_bounds__(256) void build_list(const int* __restrict__ src,
                                                  const int* __restrict__ dst,
                                                  const float* __restrict__ el,
                                                  int* __restrict__ head,
                                                  float* __restrict__ rec) {
  const int t = blockIdx.y;
  int i4 = (blockIdx.x * 256 + threadIdx.x) * 4;
  if (i4 >= EE) return;
  float* recT = rec + (size_t)t * EE * 8;
  int* headT = head + (size_t)t * NN * 2;
  const float* elT = el + (size_t)t * NN * HH;
#pragma unroll
  for (int j = 0; j < 4; ++j) {
    int i = i4 + j;
    if (i >= EE) break;
    int d = dst[(size_t)t * EE + i];
    int s = src[(size_t)t * EE + i];
    float4 ev = *(const float4*)(elT + (size_t)s * HH);
    int o = atomicExch(&headT[d * 2 + (i & 1)], i);
    float* r = recT + (size_t)i * 8;
    int4 w0 = make_int4(o, s, __float_as_int(ev.x), __float_as_int(ev.y));
    *(int4*)r = w0;
    *(float2*)(r + 4) = make_float2(ev.z, ev.w);
  }
}

// ---------------------------------------------------------------------------
// Fused per-(node,type) kernel: 32 lanes per item, 8 items per block.
// Walk BOTH dst linked lists with independent pointers (2 parallel dependency
// chains -> 2x MLP on the pointer chase). rec line carries next+src+el so the
// only other load per edge is the coalesced 512B fh segment. Single-pass
// softmax (no max shift: |e| small). lane l: channels 4l..4l+3, head h=l>>3.
// Then bias + LayerNorm(128) + ELU.
// ---------------------------------------------------------------------------
__global__ __launch_bounds__(256) void gat_node(const float* __restrict__ fh,
                                                const float* __restrict__ er,
                                                const int* __restrict__ head,
                                                const float* __restrict__ rec,
                                                const float* __restrict__ bias,
                                                const float* __restrict__ lnw,
                                                const float* __restrict__ lnb,
                                                float* __restrict__ out) {
  const int item = blockIdx.x * 8 + (threadIdx.x >> 5);  // grid covers TT*NN exactly
  const int t = item / NN;
  const int n = item % NN;
  const int l = threadIdx.x & 31;
  const int c0 = 4 * l;
  const int h = l >> 3;

  const float* recT = rec + (size_t)t * EE * 8;
  const float* fhp = fh + (size_t)t * NN * 128;
  const float erh = er[((size_t)t * NN + n) * HH + h];

  int2 hh = *(const int2*)(head + ((size_t)t * NN + n) * 2);
  int e0 = hh.x, e1 = hh.y;

  float den = 0.f;
  float ax = 0.f, ay = 0.f, az = 0.f, aw = 0.f;

  // interleaved dual-chain walk: two independent load streams
  while (e0 >= 0 && e1 >= 0) {
    const float* p0 = recT + (size_t)e0 * 8;
    const float* p1 = recT + (size_t)e1 * 8;
    int2 ns0 = *(const int2*)p0;
    int2 ns1 = *(const int2*)p1;
    float el0 = p0[2 + h];
    float el1 = p1[2 + h];
    float4 f0 = *(const float4*)(fhp + (size_t)ns0.y * 128 + c0);
    float4 f1 = *(const float4*)(fhp + (size_t)ns1.y * 128 + c0);
    float x0 = el0 + erh;
    float x1 = el1 + erh;
    x0 = (x0 > 0.f) ? x0 : NEG_SLOPE * x0;
    x1 = (x1 > 0.f) ? x1 : NEG_SLOPE * x1;
    float a0 = __expf(x0);
    float a1 = __expf(x1);
    den += a0 + a1;
    ax += a0 * f0.x + a1 * f1.x;
    ay += a0 * f0.y + a1 * f1.y;
    az += a0 * f0.z + a1 * f1.z;
    aw += a0 * f0.w + a1 * f1.w;
    e0 = ns0.x;
    e1 = ns1.x;
  }
  int e = (e0 >= 0) ? e0 : e1;
  while (e >= 0) {
    const float* pe = recT + (size_t)e * 8;
    int2 ns = *(const int2*)pe;
    float elh = pe[2 + h];
    float4 f = *(const float4*)(fhp + (size_t)ns.y * 128 + c0);
    float x = elh + erh;
    x = (x > 0.f) ? x : NEG_SLOPE * x;
    float a = __expf(x);
    den += a;
    ax += a * f.x; ay += a * f.y; az += a * f.z; aw += a * f.w;
    e = ns.x;
  }

  float inv = (den > 0.f) ? 1.f / den : 0.f;
  float hx = ax * inv + bias[t * OUTF + c0 + 0];
  float hy = ay * inv + bias[t * OUTF + c0 + 1];
  float hz = az * inv + bias[t * OUTF + c0 + 2];
  float hw = aw * inv + bias[t * OUTF + c0 + 3];

  // LayerNorm over 128 channels (4 per lane, 32 lanes)
  float s1 = hx + hy + hz + hw;
#pragma unroll
  for (int off = 16; off >= 1; off >>= 1) s1 += __shfl_xor(s1, off, 32);
  float u = s1 * (1.f / OUTF);
  float dx = hx - u, dy = hy - u, dz = hz - u, dw = hw - u;
  float s2 = dx * dx + dy * dy + dz * dz + dw * dw;
#pragma unroll
  for (int off = 16; off >= 1; off >>= 1) s2 += __shfl_xor(s2, off, 32);
  float rstd = rsqrtf(s2 * (1.f / OUTF) + LN_EPS);

  float4 wv = *(const float4*)(lnw + t * OUTF + c0);
  float4 bv = *(const float4*)(lnb + t * OUTF + c0);
  float y0 = wv.x * (dx * rstd) + bv.x;
  float y1 = wv.y * (dy * rstd) + bv.y;
  float y2 = wv.z * (dz * rstd) + bv.z;
  float y3 = wv.w * (dw * rstd) + bv.w;
  y0 = (y0 > 0.f) ? y0 : expm1f(y0);
  y1 = (y1 > 0.f) ? y1 : expm1f(y1);
  y2 = (y2 > 0.f) ? y2 : expm1f(y2);
  y3 = (y3 > 0.f) ? y3 : expm1f(y3);

  *(float4*)(out + ((size_t)n * TT + t) * OUTF + c0) = make_float4(y0, y1, y2, y3);
}

// ---------------------------------------------------------------------------
extern "C" void kernel_launch(void* const* d_in, const int* in_sizes, int n_in,
                              void* d_out, int out_size, void* d_ws, size_t ws_size,
                              hipStream_t stream) {
  const float* feature = (const float*)d_in[0];
  const int* src = (const int*)d_in[1];
  const int* dst = (const int*)d_in[2];
  const float* W = (const float*)d_in[3];
  const float* al = (const float*)d_in[4];
  const float* ar = (const float*)d_in[5];
  const float* bias = (const float*)d_in[6];
  const float* lnw = (const float*)d_in[7];
  const float* lnb = (const float*)d_in[8];
  float* out = (float*)d_out;

  char* ws = (char*)d_ws;
  size_t off = 0;
  auto carve = [&](size_t bytes) -> void* {
    void* p = ws + off;
    off += (bytes + 511) & ~(size_t)511;
    return p;
  };
  float* fh = (float*)carve((size_t)TT * NN * 128 * 4);   // 51.2 MB
  float* el = (float*)carve((size_t)TT * NN * HH * 4);
  float* er = (float*)carve((size_t)TT * NN * HH * 4);
  int* head = (int*)carve((size_t)TT * NN * 2 * 4);       // 0.8 MB (2 lists/node)
  float* rec = (float*)carve((size_t)TT * EE * 32);       // 51.2 MB (32B/edge)

  hipMemsetAsync(head, 0xFF, (size_t)TT * NN * 2 * 4, stream);  // heads = -1

  gemm_fh_elr<<<dim3((NN + GM - 1) / GM, TT), 256, 0, stream>>>(feature, W, al, ar, fh, el, er);
  build_list<<<dim3((EE / 4 + 255) / 256, TT), 256, 0, stream>>>(src, dst, el, head, rec);
  gat_node<<<(TT * NN) / 8, 256, 0, stream>>>(fh, er, head, rec,
                                              bias, lnw, lnb, out);
}

// Round 13
// 322.559 us; speedup vs baseline: 2.2750x; 1.1124x over previous
//
#include <hip/hip_runtime.h>
#include <hip/hip_fp16.h>
#include <math.h>

#define NN 50000
#define EE 800000
#define TT 2
#define HH 4
#define OUTF 128

constexpr float NEG_SLOPE = 0.2f;
constexpr float LN_EPS = 1e-12f;

// ---------------------------------------------------------------------------
// GEMM: fh16[t] = (feature @ W[t]) as fp16 + fused el/er epilogue (fp32)
// block: 256 threads, tile 64 rows x 128 cols, K-chunks of 32
// ---------------------------------------------------------------------------
#define GM 64
#define KB 32
#define APAD 36
#define WPAD 132

static __device__ __forceinline__ unsigned pack_h2(float a, float b) {
  __half2 h = __floats2half2_rn(a, b);
  return *reinterpret_cast<unsigned*>(&h);
}

__global__ __launch_bounds__(256) void gemm_fh_elr(const float* __restrict__ A,
                                                   const float* __restrict__ W,
                                                   const float* __restrict__ al,
                                                   const float* __restrict__ ar,
                                                   __half* __restrict__ fh16,
                                                   float* __restrict__ el,
                                                   float* __restrict__ er) {
  __shared__ float As[GM][APAD];
  __shared__ float Ws[KB][WPAD];
  const int t = blockIdx.y;
  const int row0 = blockIdx.x * GM;
  const int tid = threadIdx.x;
  const int tcol = tid & 15;
  const int trow = tid >> 4;
  const float* Wt = W + (size_t)t * 128 * 128;

  float acc[4][8];
#pragma unroll
  for (int i = 0; i < 4; ++i)
#pragma unroll
    for (int j = 0; j < 8; ++j) acc[i][j] = 0.f;

  for (int kk = 0; kk < 128; kk += KB) {
#pragma unroll
    for (int j = 0; j < 2; ++j) {
      int f = tid + 256 * j;
      int r = f >> 3, kq = f & 7;
      int grow = row0 + r;
      float4 v = make_float4(0.f, 0.f, 0.f, 0.f);
      if (grow < NN) v = *(const float4*)(A + (size_t)grow * 128 + kk + kq * 4);
      *(float4*)&As[r][kq * 4] = v;
    }
#pragma unroll
    for (int j = 0; j < 4; ++j) {
      int f = tid + 256 * j;
      int kq = f >> 5, c4 = f & 31;
      float4 v = *(const float4*)(Wt + (size_t)(kk + kq) * 128 + c4 * 4);
      *(float4*)&Ws[kq][c4 * 4] = v;
    }
    __syncthreads();
#pragma unroll
    for (int k = 0; k < KB; ++k) {
      float a0 = As[4 * trow + 0][k];
      float a1 = As[4 * trow + 1][k];
      float a2 = As[4 * trow + 2][k];
      float a3 = As[4 * trow + 3][k];
      float4 b0 = *(const float4*)&Ws[k][4 * tcol];
      float4 b1 = *(const float4*)&Ws[k][64 + 4 * tcol];
      acc[0][0] += a0 * b0.x; acc[0][1] += a0 * b0.y; acc[0][2] += a0 * b0.z; acc[0][3] += a0 * b0.w;
      acc[0][4] += a0 * b1.x; acc[0][5] += a0 * b1.y; acc[0][6] += a0 * b1.z; acc[0][7] += a0 * b1.w;
      acc[1][0] += a1 * b0.x; acc[1][1] += a1 * b0.y; acc[1][2] += a1 * b0.z; acc[1][3] += a1 * b0.w;
      acc[1][4] += a1 * b1.x; acc[1][5] += a1 * b1.y; acc[1][6] += a1 * b1.z; acc[1][7] += a1 * b1.w;
      acc[2][0] += a2 * b0.x; acc[2][1] += a2 * b0.y; acc[2][2] += a2 * b0.z; acc[2][3] += a2 * b0.w;
      acc[2][4] += a2 * b1.x; acc[2][5] += a2 * b1.y; acc[2][6] += a2 * b1.z; acc[2][7] += a2 * b1.w;
      acc[3][0] += a3 * b0.x; acc[3][1] += a3 * b0.y; acc[3][2] += a3 * b0.z; acc[3][3] += a3 * b0.w;
      acc[3][4] += a3 * b1.x; acc[3][5] += a3 * b1.y; acc[3][6] += a3 * b1.z; acc[3][7] += a3 * b1.w;
    }
    __syncthreads();
  }
  // store fh16 tile (fp16, 8B per thread per row-half)
#pragma unroll
  for (int i = 0; i < 4; ++i) {
    int grow = row0 + 4 * trow + i;
    if (grow < NN) {
      __half* o = fh16 + ((size_t)t * NN + grow) * 128;
      unsigned u0 = pack_h2(acc[i][0], acc[i][1]);
      unsigned u1 = pack_h2(acc[i][2], acc[i][3]);
      unsigned u2 = pack_h2(acc[i][4], acc[i][5]);
      unsigned u3 = pack_h2(acc[i][6], acc[i][7]);
      *(uint2*)(o + 4 * tcol) = make_uint2(u0, u1);
      *(uint2*)(o + 64 + 4 * tcol) = make_uint2(u2, u3);
    }
  }
  // fused el/er epilogue (fp32, reduce across the 8-thread tcol-octet)
  const int ha = tcol >> 3;
  const int ci = (4 * tcol) & 31;
  float4 alA = *(const float4*)(al + (size_t)(t * HH + ha) * 32 + ci);
  float4 arA = *(const float4*)(ar + (size_t)(t * HH + ha) * 32 + ci);
  float4 alB = *(const float4*)(al + (size_t)(t * HH + 2 + ha) * 32 + ci);
  float4 arB = *(const float4*)(ar + (size_t)(t * HH + 2 + ha) * 32 + ci);
#pragma unroll
  for (int i = 0; i < 4; ++i) {
    float pla = acc[i][0] * alA.x + acc[i][1] * alA.y + acc[i][2] * alA.z + acc[i][3] * alA.w;
    float pra = acc[i][0] * arA.x + acc[i][1] * arA.y + acc[i][2] * arA.z + acc[i][3] * arA.w;
    float plb = acc[i][4] * alB.x + acc[i][5] * alB.y + acc[i][6] * alB.z + acc[i][7] * alB.w;
    float prb = acc[i][4] * arB.x + acc[i][5] * arB.y + acc[i][6] * arB.z + acc[i][7] * arB.w;
#pragma unroll
    for (int off = 1; off <= 4; off <<= 1) {
      pla += __shfl_xor(pla, off, 64);
      pra += __shfl_xor(pra, off, 64);
      plb += __shfl_xor(plb, off, 64);
      prb += __shfl_xor(prb, off, 64);
    }
    if ((tcol & 7) == 0) {
      int row = row0 + 4 * trow + i;
      if (row < NN) {
        size_t base = ((size_t)t * NN + row) * HH;
        el[base + ha] = pla;
        er[base + ha] = pra;
        el[base + 2 + ha] = plb;
        er[base + 2 + ha] = prb;
      }
    }
  }
}

// ---------------------------------------------------------------------------
// TWO per-dst linked lists (edge parity i&1) with fat records (32B):
//   rec[e] = {next, src, el[src][0..3] fp32, pad2}
// ---------------------------------------------------------------------------
__global__ __launch_bounds__(256) void build_list(const int* __restrict__ src,
                                                  const int* __restrict__ dst,
                                                  const float* __restrict__ el,
                                                  int* __restrict__ head,
                                                  float* __restrict__ rec) {
  const int t = blockIdx.y;
  int i4 = (blockIdx.x * 256 + threadIdx.x) * 4;
  if (i4 >= EE) return;
  float* recT = rec + (size_t)t * EE * 8;
  int* headT = head + (size_t)t * NN * 2;
  const float* elT = el + (size_t)t * NN * HH;
#pragma unroll
  for (int j = 0; j < 4; ++j) {
    int i = i4 + j;
    if (i >= EE) break;
    int d = dst[(size_t)t * EE + i];
    int s = src[(size_t)t * EE + i];
    float4 ev = *(const float4*)(elT + (size_t)s * HH);
    int o = atomicExch(&headT[d * 2 + (i & 1)], i);
    float* r = recT + (size_t)i * 8;
    int4 w0 = make_int4(o, s, __float_as_int(ev.x), __float_as_int(ev.y));
    *(int4*)r = w0;
    *(float2*)(r + 4) = make_float2(ev.z, ev.w);
  }
}

// ---------------------------------------------------------------------------
// Fused per-(node,type) kernel: 32 lanes per item, 8 items per block.
// Dual-chain walk; per edge: 1 rec line (broadcast) + 256B coalesced fh16.
// Single-pass softmax (no max shift: |e| small). lane l: channels 4l..4l+3.
// Then bias + LayerNorm(128) + ELU (fp32 throughout).
// ---------------------------------------------------------------------------
__global__ __launch_bounds__(256) void gat_node(const __half* __restrict__ fh16,
                                                const float* __restrict__ er,
                                                const int* __restrict__ head,
                                                const float* __restrict__ rec,
                                                const float* __restrict__ bias,
                                                const float* __restrict__ lnw,
                                                const float* __restrict__ lnb,
                                                float* __restrict__ out) {
  const int item = blockIdx.x * 8 + (threadIdx.x >> 5);  // grid covers TT*NN exactly
  const int t = item / NN;
  const int n = item % NN;
  const int l = threadIdx.x & 31;
  const int c0 = 4 * l;
  const int h = l >> 3;

  const float* recT = rec + (size_t)t * EE * 8;
  const __half* fhp = fh16 + (size_t)t * NN * 128;
  const float erh = er[((size_t)t * NN + n) * HH + h];

  int2 hh = *(const int2*)(head + ((size_t)t * NN + n) * 2);
  int e0 = hh.x, e1 = hh.y;

  float den = 0.f;
  float ax = 0.f, ay = 0.f, az = 0.f, aw = 0.f;

  while (e0 >= 0 && e1 >= 0) {
    const float* p0 = recT + (size_t)e0 * 8;
    const float* p1 = recT + (size_t)e1 * 8;
    int2 ns0 = *(const int2*)p0;
    int2 ns1 = *(const int2*)p1;
    float el0 = p0[2 + h];
    float el1 = p1[2 + h];
    uint2 fu0 = *(const uint2*)(fhp + (size_t)ns0.y * 128 + c0);
    uint2 fu1 = *(const uint2*)(fhp + (size_t)ns1.y * 128 + c0);
    float2 f0a = __half22float2(*reinterpret_cast<const __half2*>(&fu0.x));
    float2 f0b = __half22float2(*reinterpret_cast<const __half2*>(&fu0.y));
    float2 f1a = __half22float2(*reinterpret_cast<const __half2*>(&fu1.x));
    float2 f1b = __half22float2(*reinterpret_cast<const __half2*>(&fu1.y));
    float x0 = el0 + erh;
    float x1 = el1 + erh;
    x0 = (x0 > 0.f) ? x0 : NEG_SLOPE * x0;
    x1 = (x1 > 0.f) ? x1 : NEG_SLOPE * x1;
    float a0 = __expf(x0);
    float a1 = __expf(x1);
    den += a0 + a1;
    ax += a0 * f0a.x + a1 * f1a.x;
    ay += a0 * f0a.y + a1 * f1a.y;
    az += a0 * f0b.x + a1 * f1b.x;
    aw += a0 * f0b.y + a1 * f1b.y;
    e0 = ns0.x;
    e1 = ns1.x;
  }
  int e = (e0 >= 0) ? e0 : e1;
  while (e >= 0) {
    const float* pe = recT + (size_t)e * 8;
    int2 ns = *(const int2*)pe;
    float elh = pe[2 + h];
    uint2 fu = *(const uint2*)(fhp + (size_t)ns.y * 128 + c0);
    float2 fa = __half22float2(*reinterpret_cast<const __half2*>(&fu.x));
    float2 fb = __half22float2(*reinterpret_cast<const __half2*>(&fu.y));
    float x = elh + erh;
    x = (x > 0.f) ? x : NEG_SLOPE * x;
    float a = __expf(x);
    den += a;
    ax += a * fa.x; ay += a * fa.y; az += a * fb.x; aw += a * fb.y;
    e = ns.x;
  }

  float inv = (den > 0.f) ? 1.f / den : 0.f;
  float hx = ax * inv + bias[t * OUTF + c0 + 0];
  float hy = ay * inv + bias[t * OUTF + c0 + 1];
  float hz = az * inv + bias[t * OUTF + c0 + 2];
  float hw = aw * inv + bias[t * OUTF + c0 + 3];

  // LayerNorm over 128 channels (4 per lane, 32 lanes)
  float s1 = hx + hy + hz + hw;
#pragma unroll
  for (int off = 16; off >= 1; off >>= 1) s1 += __shfl_xor(s1, off, 32);
  float u = s1 * (1.f / OUTF);
  float dx = hx - u, dy = hy - u, dz = hz - u, dw = hw - u;
  float s2 = dx * dx + dy * dy + dz * dz + dw * dw;
#pragma unroll
  for (int off = 16; off >= 1; off >>= 1) s2 += __shfl_xor(s2, off, 32);
  float rstd = rsqrtf(s2 * (1.f / OUTF) + LN_EPS);

  float4 wv = *(const float4*)(lnw + t * OUTF + c0);
  float4 bv = *(const float4*)(lnb + t * OUTF + c0);
  float y0 = wv.x * (dx * rstd) + bv.x;
  float y1 = wv.y * (dy * rstd) + bv.y;
  float y2 = wv.z * (dz * rstd) + bv.z;
  float y3 = wv.w * (dw * rstd) + bv.w;
  y0 = (y0 > 0.f) ? y0 : expm1f(y0);
  y1 = (y1 > 0.f) ? y1 : expm1f(y1);
  y2 = (y2 > 0.f) ? y2 : expm1f(y2);
  y3 = (y3 > 0.f) ? y3 : expm1f(y3);

  *(float4*)(out + ((size_t)n * TT + t) * OUTF + c0) = make_float4(y0, y1, y2, y3);
}

// ---------------------------------------------------------------------------
extern "C" void kernel_launch(void* const* d_in, const int* in_sizes, int n_in,
                              void* d_out, int out_size, void* d_ws, size_t ws_size,
                              hipStream_t stream) {
  const float* feature = (const float*)d_in[0];
  const int* src = (const int*)d_in[1];
  const int* dst = (const int*)d_in[2];
  const float* W = (const float*)d_in[3];
  const float* al = (const float*)d_in[4];
  const float* ar = (const float*)d_in[5];
  const float* bias = (const float*)d_in[6];
  const float* lnw = (const float*)d_in[7];
  const float* lnb = (const float*)d_in[8];
  float* out = (float*)d_out;

  char* ws = (char*)d_ws;
  size_t off = 0;
  auto carve = [&](size_t bytes) -> void* {
    void* p = ws + off;
    off += (bytes + 511) & ~(size_t)511;
    return p;
  };
  __half* fh16 = (__half*)carve((size_t)TT * NN * 128 * 2);  // 25.6 MB
  float* el = (float*)carve((size_t)TT * NN * HH * 4);
  float* er = (float*)carve((size_t)TT * NN * HH * 4);
  int* head = (int*)carve((size_t)TT * NN * 2 * 4);          // 0.8 MB (2 lists/node)
  float* rec = (float*)carve((size_t)TT * EE * 32);          // 51.2 MB (32B/edge)

  (void)hipMemsetAsync(head, 0xFF, (size_t)TT * NN * 2 * 4, stream);  // heads = -1

  gemm_fh_elr<<<dim3((NN + GM - 1) / GM, TT), 256, 0, stream>>>(feature, W, al, ar, fh16, el, er);
  build_list<<<dim3((EE / 4 + 255) / 256, TT), 256, 0, stream>>>(src, dst, el, head, rec);
  gat_node<<<(TT * NN) / 8, 256, 0, stream>>>(fh16, er, head, rec,
                                              bias, lnw, lnb, out);
}